// Round 1
// baseline (220.505 us; speedup 1.0000x reference)
//
#include <hip/hip_runtime.h>

#define B_DIM 8
#define T_DIM 2048
#define C_DIM 1024
#define H_DIM 128

typedef __attribute__((ext_vector_type(8))) short bf16x8;
typedef __attribute__((ext_vector_type(4))) float f32x4;

__device__ __forceinline__ short f2bf(float f) {
  union { float f; unsigned u; } v; v.f = f;
  unsigned u = v.u;
  unsigned r = (u + 0x7FFFu + ((u >> 16) & 1u)) >> 16;
  return (short)r;
}

__device__ __forceinline__ void gload_lds16(const short* g, short* l) {
  __builtin_amdgcn_global_load_lds(
      (const __attribute__((address_space(1))) void*)g,
      (__attribute__((address_space(3))) void*)l, 16, 0, 0);
}

// ---------------------------------------------------------------------------
// Kernel 1: prep.  (a) x fp32 -> bf16 (xb, [B*T][C]).  (b) weights fp32 ->
// bf16 transposed: Wt[3][H=128][C=1024], 16B coalesced writes.
// ---------------------------------------------------------------------------
#define NXE ((B_DIM * T_DIM * C_DIM) / 8)   // 2097152 x-items (8 elems each)
#define NWE ((3 * C_DIM * H_DIM) / 8)       // 49152 w-items

__global__ __launch_bounds__(256) void prep_kernel(
    const float* __restrict__ x, const float* __restrict__ Wk,
    const float* __restrict__ Wq, const float* __restrict__ Wv,
    short* __restrict__ xb, short* __restrict__ Wt) {
  int gid = blockIdx.x * 256 + threadIdx.x;
  if (gid < NXE) {
    const float* src = x + (size_t)gid * 8;
    float4 f0 = ((const float4*)src)[0];
    float4 f1 = ((const float4*)src)[1];
    __attribute__((aligned(16))) short t[8];
    t[0] = f2bf(f0.x); t[1] = f2bf(f0.y); t[2] = f2bf(f0.z); t[3] = f2bf(f0.w);
    t[4] = f2bf(f1.x); t[5] = f2bf(f1.y); t[6] = f2bf(f1.z); t[7] = f2bf(f1.w);
    ((int4*)xb)[gid] = *(const int4*)t;
  } else {
    int j = gid - NXE;
    if (j >= NWE) return;
    int w = j >> 14;             // /16384 items per weight
    int r = j & 16383;
    int h = r >> 7;              // C/8 = 128 items per h
    int c0 = (r & 127) * 8;
    const float* W = (w == 0) ? Wk : ((w == 1) ? Wq : Wv);
    __attribute__((aligned(16))) short t[8];
#pragma unroll
    for (int i = 0; i < 8; i++) t[i] = f2bf(W[(size_t)(c0 + i) * H_DIM + h]);
    *(int4*)(Wt + (size_t)w * (C_DIM * H_DIM) + h * C_DIM + c0) = *(const int4*)t;
  }
}

// ---------------------------------------------------------------------------
// Kernel 2: projection GEMM (m97 structure: linear LDS + global_load_lds x16).
// out[m][h] = sum_c xb[m][c] * Wt[wi][h][c].  Tile 128x128, BK=32, 4 waves.
// wi = 0 -> K, 1 -> Q (row-major [t][h]), 2 -> V transposed ([h][t]).
// ---------------------------------------------------------------------------
__global__ __launch_bounds__(256) void proj_kernel(
    const short* __restrict__ xb, const short* __restrict__ Wt,
    short* __restrict__ Kb, short* __restrict__ Qb, short* __restrict__ Vt) {
  const int wi = blockIdx.y;
  const int m0 = blockIdx.x * 128;
  __shared__ short As[128 * 32];   // linear [row][32] (gload_lds needs linear)
  __shared__ short Bs[128 * 32];
  const int tid  = threadIdx.x;
  const int lane = tid & 63;
  const int wv   = tid >> 6;
  const int n    = lane & 15;
  const int quad = lane >> 4;
  const int mbase = (wv >> 1) * 64;
  const int nbase = (wv & 1) * 64;
  const short* Wp = Wt + (size_t)wi * (C_DIM * H_DIM);

  const int lrow = lane >> 2;        // 0..15 row-within-chunk
  const int lcol = (lane & 3) * 8;   // 0,8,16,24

  f32x4 acc[4][4];
#pragma unroll
  for (int i = 0; i < 4; i++)
#pragma unroll
    for (int j = 0; j < 4; j++) {
      f32x4 z = {0.f, 0.f, 0.f, 0.f};
      acc[i][j] = z;
    }

  for (int k0 = 0; k0 < C_DIM; k0 += 32) {
    __syncthreads();
    // stage A and B: 8 chunks each of 1KB (64 lanes x 16B), 2 chunks/wave
#pragma unroll
    for (int h = 0; h < 2; h++) {
      int ch = wv * 2 + h;                 // wave-uniform
      int row = ch * 16 + lrow;
      gload_lds16(xb + (size_t)(m0 + row) * C_DIM + k0 + lcol, &As[ch * 512]);
      gload_lds16(Wp + (size_t)row * C_DIM + k0 + lcol, &Bs[ch * 512]);
    }
    __syncthreads();   // compiler drains vmcnt here (m97 structure)

    bf16x8 aF[4], bF[4];
#pragma unroll
    for (int mt = 0; mt < 4; mt++)
      aF[mt] = *(const bf16x8*)&As[(mbase + mt * 16 + n) * 32 + quad * 8];
#pragma unroll
    for (int nt = 0; nt < 4; nt++)
      bF[nt] = *(const bf16x8*)&Bs[(nbase + nt * 16 + n) * 32 + quad * 8];
#pragma unroll
    for (int mt = 0; mt < 4; mt++)
#pragma unroll
      for (int nt = 0; nt < 4; nt++)
        acc[mt][nt] = __builtin_amdgcn_mfma_f32_16x16x32_bf16(
            aF[mt], bF[nt], acc[mt][nt], 0, 0, 0);
  }

  // epilogue: C/D layout col = lane&15, row = quad*4 + reg
#pragma unroll
  for (int mt = 0; mt < 4; mt++) {
#pragma unroll
    for (int nt = 0; nt < 4; nt++) {
#pragma unroll
      for (int i = 0; i < 4; i++) {
        int row = m0 + mbase + mt * 16 + quad * 4 + i;   // token index
        int col = nbase + nt * 16 + n;                   // h index
        short v = f2bf(acc[mt][nt][i]);
        if (wi == 0) {
          Kb[(size_t)row * H_DIM + col] = v;
        } else if (wi == 1) {
          Qb[(size_t)row * H_DIM + col] = v;
        } else {
          int bb = row >> 11;
          int t = row & (T_DIM - 1);
          Vt[((size_t)bb * H_DIM + col) * T_DIM + t] = v;
        }
      }
    }
  }
}

// ---------------------------------------------------------------------------
// Kernel 3: causal flash attention, 512 threads = 8 waves.
// Waves 0-3 (g=0) process even KV tiles, waves 4-7 (g=1) odd tiles, each
// group with its own online-softmax state; merged in LDS at the end.
// -> 2 waves/SIMD occupancy and critical path halved (max 16 iters, was 32).
// K/V staged via reg-prefetch (T14); raw s_barrier + lgkmcnt-only waits keep
// the global prefetch in flight across barriers (T4); LDS XOR-swizzled (T2).
// ---------------------------------------------------------------------------
__global__ __launch_bounds__(512) void attn_kernel(
    const short* __restrict__ Qb, const short* __restrict__ Kb,
    const short* __restrict__ Vt, float* __restrict__ out) {
  const int b  = blockIdx.y;
  const int q0 = blockIdx.x * 64;
  const int tid  = threadIdx.x;
  const int lane = tid & 63;
  const int wv   = tid >> 6;   // 0..7
  const int g    = wv >> 2;    // KV parity group
  const int ws   = wv & 3;     // q-strip (16 rows) within the 64-row block
  const int n    = lane & 15;
  const int quad = lane >> 4;
  const int gtid = tid & 255;  // thread id within group

  __shared__ short Ks[2][64 * 128];   // [g][kv][h], XOR-swizzled, 32KB
  __shared__ short Vs[2][128 * 64];   // [g][h][t],  XOR-swizzled, 32KB
  __shared__ short Ps[8][16][72];     // per-wave P strips, 18KB

  const int ntiles = (q0 >> 6) + 1;
  const int niter  = (ntiles + 1) >> 1;

  // Q A-frags: rows q0 + ws*16 + n
  bf16x8 aQ[4];
  {
    const short* qrow = Qb + (size_t)(b * T_DIM + q0 + ws * 16 + n) * H_DIM;
#pragma unroll
    for (int kc = 0; kc < 4; kc++)
      aQ[kc] = *(const bf16x8*)(qrow + kc * 32 + quad * 8);
  }

  f32x4 accO[8];
#pragma unroll
  for (int i = 0; i < 8; i++) {
    f32x4 z = {0.f, 0.f, 0.f, 0.f};
    accO[i] = z;
  }
  float mrow[4] = {-1e30f, -1e30f, -1e30f, -1e30f};
  float lrow[4] = {0.f, 0.f, 0.f, 0.f};
  const float scale = 0.08838834764831845f;  // 1/sqrt(128)
  const int row0 = q0 + ws * 16 + quad * 4;  // + reg i

  int4 kreg[4], vreg[4];
  char* ksb = (char*)Ks[g];
  char* vsb = (char*)Vs[g];

  auto LOADR = [&](int t) {   // global -> regs, fully coalesced 16B/lane
    int j0 = t * 64;
#pragma unroll
    for (int p = 0; p < 4; p++) {
      int cid = gtid + p * 256;
      kreg[p] = *(const int4*)(Kb +
          (size_t)(b * T_DIM + j0 + (cid >> 4)) * H_DIM + (cid & 15) * 8);
      vreg[p] = *(const int4*)(Vt +
          ((size_t)b * H_DIM + (cid >> 3)) * T_DIM + j0 + (cid & 7) * 8);
    }
  };
  auto STORELDS = [&]() {     // regs -> swizzled LDS (byte ^= (row&7)<<4)
#pragma unroll
    for (int p = 0; p < 4; p++) {
      int cid = gtid + p * 256;
      int kr = cid >> 4;
      *(int4*)(ksb + kr * 256 + (((cid & 15) * 16) ^ ((kr & 7) << 4))) = kreg[p];
      int vr = cid >> 3;
      *(int4*)(vsb + vr * 128 + (((cid & 7) * 16) ^ ((vr & 7) << 4))) = vreg[p];
    }
  };

  // prologue: stage this group's first tile
  if (g < ntiles) { LOADR(g); STORELDS(); }

  for (int it = 0; it < niter; ++it) {
    const int t = 2 * it + g;
    const bool act = t < ntiles;
    const bool pre = (t + 2) < ntiles;
    if (pre) LOADR(t + 2);   // prefetch stays in flight across the barrier
    asm volatile("s_waitcnt lgkmcnt(0)" ::: "memory");  // drain LDS writes only
    __builtin_amdgcn_s_barrier();
    __builtin_amdgcn_sched_barrier(0);
    if (act) {
      const int j0 = t * 64;
      // S = Q K^T (16 x 64 per wave)
      f32x4 accS[4];
#pragma unroll
      for (int nt = 0; nt < 4; nt++) {
        f32x4 z = {0.f, 0.f, 0.f, 0.f};
        accS[nt] = z;
      }
#pragma unroll
      for (int nt = 0; nt < 4; nt++) {
        const int r = nt * 16 + n;
        const int rx = (r & 7) << 4;
#pragma unroll
        for (int kc = 0; kc < 4; kc++) {
          bf16x8 bK = *(const bf16x8*)(ksb + r * 256 + ((kc * 64 + quad * 16) ^ rx));
          accS[nt] = __builtin_amdgcn_mfma_f32_16x16x32_bf16(aQ[kc], bK, accS[nt], 0, 0, 0);
        }
      }
      // scale + causal mask + online softmax
      float sv[4][4];
      float mt4[4] = {-1e30f, -1e30f, -1e30f, -1e30f};
#pragma unroll
      for (int nt = 0; nt < 4; nt++) {
        int col = j0 + nt * 16 + n;
#pragma unroll
        for (int i = 0; i < 4; i++) {
          float s = accS[nt][i] * scale;
          if (col > row0 + i) s = -1e30f;
          sv[nt][i] = s;
          mt4[i] = fmaxf(mt4[i], s);
        }
      }
#pragma unroll
      for (int i = 0; i < 4; i++) {
#pragma unroll
        for (int off = 1; off < 16; off <<= 1)
          mt4[i] = fmaxf(mt4[i], __shfl_xor(mt4[i], off, 64));
      }
      float alpha[4], rsum[4];
#pragma unroll
      for (int i = 0; i < 4; i++) {
        float mnew = fmaxf(mrow[i], mt4[i]);
        alpha[i] = __expf(mrow[i] - mnew);
        mrow[i] = mnew;
        rsum[i] = 0.f;
      }
#pragma unroll
      for (int nt = 0; nt < 4; nt++)
#pragma unroll
        for (int i = 0; i < 4; i++) {
          float p = __expf(sv[nt][i] - mrow[i]);
          rsum[i] += p;
          Ps[wv][quad * 4 + i][nt * 16 + n] = f2bf(p);
        }
#pragma unroll
      for (int i = 0; i < 4; i++) {
#pragma unroll
        for (int off = 1; off < 16; off <<= 1)
          rsum[i] += __shfl_xor(rsum[i], off, 64);
        lrow[i] = lrow[i] * alpha[i] + rsum[i];
      }
#pragma unroll
      for (int ht = 0; ht < 8; ht++)
#pragma unroll
        for (int i = 0; i < 4; i++)
          accO[ht][i] *= alpha[i];

      // P strip is written and read by the SAME wave: lgkmcnt wait suffices
      asm volatile("s_waitcnt lgkmcnt(0)" ::: "memory");
      __builtin_amdgcn_sched_barrier(0);

      bf16x8 aP[2];
#pragma unroll
      for (int kc = 0; kc < 2; kc++)
        aP[kc] = *(const bf16x8*)&Ps[wv][n][kc * 32 + quad * 8];
#pragma unroll
      for (int ht = 0; ht < 8; ht++) {
        const int r = ht * 16 + n;
        const int rx = (r & 7) << 4;
#pragma unroll
        for (int kc = 0; kc < 2; kc++) {
          bf16x8 bV = *(const bf16x8*)(vsb + r * 128 + ((kc * 64 + quad * 16) ^ rx));
          accO[ht] = __builtin_amdgcn_mfma_f32_16x16x32_bf16(aP[kc], bV, accO[ht], 0, 0, 0);
        }
      }
    }
    __builtin_amdgcn_s_barrier();   // all reads of tile t done (LDS reads were
    __builtin_amdgcn_sched_barrier(0);  // drained by MFMA-consumption waits)
    if (pre) STORELDS();
  }

  // merge the two groups' partial softmax states (reuse Ks/Vs LDS)
  float* ob  = (float*)Ks[0];   // [64 rows][128] f32 = 32KB (exactly Ks)
  float* mlb = (float*)Vs[0];   // [64 rows][2] f32
  if (g == 1) {
#pragma unroll
    for (int i = 0; i < 4; i++) {
      int r = ws * 16 + quad * 4 + i;
#pragma unroll
      for (int ht = 0; ht < 8; ht++)
        ob[r * 128 + ht * 16 + n] = accO[ht][i];
      if (n == 0) { mlb[r * 2] = mrow[i]; mlb[r * 2 + 1] = lrow[i]; }
    }
  }
  __syncthreads();
  if (g == 0) {
#pragma unroll
    for (int i = 0; i < 4; i++) {
      int r = ws * 16 + quad * 4 + i;
      float m1 = mlb[r * 2], l1 = mlb[r * 2 + 1];
      float mnew = fmaxf(mrow[i], m1);
      float a0 = __expf(mrow[i] - mnew);
      float a1 = __expf(m1 - mnew);     // 0 when group 1 had no tiles
      float linv = 1.0f / (lrow[i] * a0 + l1 * a1);
      size_t base = (size_t)(b * T_DIM + q0 + r) * H_DIM;
#pragma unroll
      for (int ht = 0; ht < 8; ht++)
        out[base + ht * 16 + n] =
            (accO[ht][i] * a0 + ob[r * 128 + ht * 16 + n] * a1) * linv;
    }
  }
}

// ---------------------------------------------------------------------------
extern "C" void kernel_launch(void* const* d_in, const int* in_sizes, int n_in,
                              void* d_out, int out_size, void* d_ws, size_t ws_size,
                              hipStream_t stream) {
  (void)in_sizes; (void)n_in; (void)out_size; (void)ws_size;
  const float* x  = (const float*)d_in[0];
  const float* Wk = (const float*)d_in[1];
  const float* Wq = (const float*)d_in[2];
  const float* Wv = (const float*)d_in[3];
  float* out = (float*)d_out;

  char* ws = (char*)d_ws;
  short* Wt = (short*)ws;                               // 786,432 B
  short* Kb = (short*)(ws + 786432);                    // 4 MB
  short* Qb = (short*)(ws + 786432 + 4194304);          // 4 MB
  short* Vt = (short*)(ws + 786432 + 8388608);          // [8][128][2048] bf16, 4 MB
  short* xb = (short*)(ws + 786432 + 12582912);         // [B*T][C] bf16, 32 MB

  prep_kernel<<<dim3((NXE + NWE) / 256), dim3(256), 0, stream>>>(x, Wk, Wq, Wv, xb, Wt);
  proj_kernel<<<dim3(128, 3), dim3(256), 0, stream>>>(xb, Wt, Kb, Qb, Vt);
  attn_kernel<<<dim3(T_DIM / 64, B_DIM), dim3(512), 0, stream>>>(Qb, Kb, Vt, out);
}